// Round 1
// baseline (8336.565 us; speedup 1.0000x reference)
//
#include <hip/hip_runtime.h>
#include <math.h>

#define BB   64      // batch
#define TT_  1024    // sequence length
#define UU   512     // hidden units
#define VV   256     // vocab (output)
#define EE   256     // embedding dim
#define TC   128     // time chunk

// ---------------- E2 = emb @ Wx + b : [256, 512] ----------------
__global__ __launch_bounds__(512) void e2_kernel(
    const float* __restrict__ emb, const float* __restrict__ Wx,
    const float* __restrict__ bias, float* __restrict__ E2)
{
    const int v = blockIdx.x;
    const int u = threadIdx.x;
    float acc = bias[u];
    const float* er = emb + v * EE;
    #pragma unroll 8
    for (int e = 0; e < EE; ++e)
        acc = fmaf(er[e], Wx[e * UU + u], acc);
    E2[v * UU + u] = acc;
}

// ---------------- recurrence over one time chunk ----------------
// grid: 64 blocks (one per batch element), 512 threads.
// k-split: group g = tid>>7 handles k in [g*128, g*128+128)
// unit-split: l = tid&127 handles units [4l, 4l+4) via float4 loads of Wh.
__global__ __launch_bounds__(512) void rnn_chunk_kernel(
    const int* __restrict__ toks, const float* __restrict__ E2,
    const float* __restrict__ Wh, float* __restrict__ hcarry,
    float* __restrict__ hs, int t0, int first)
{
    __shared__ float  hsh[UU];
    __shared__ float4 red[3][128];
    __shared__ int    stok[TC];

    const int b   = blockIdx.x;
    const int tid = threadIdx.x;
    const int g   = tid >> 7;       // 0..3
    const int l   = tid & 127;      // 0..127

    float4* hsh4 = (float4*)hsh;

    if (tid < TC) stok[tid] = toks[b * TT_ + t0 + tid];
    if (tid < 128) {
        if (first) hsh4[tid] = make_float4(0.f, 0.f, 0.f, 0.f);
        else       hsh4[tid] = ((const float4*)(hcarry + b * UU))[tid];
    }
    __syncthreads();

    const float4* Wh4 = (const float4*)Wh;   // [512][128] of float4
    const float4* E24 = (const float4*)E2;   // [256][128] of float4

    for (int tt = 0; tt < TC; ++tt) {
        const int tok = stok[tt];
        float4 acc;
        if (g == 0) acc = E24[tok * 128 + l];
        else        acc = make_float4(0.f, 0.f, 0.f, 0.f);

        const float4* hp = hsh4 + g * 32;            // broadcast reads
        const float4* wp = Wh4 + (g * 128) * 128 + l;
        #pragma unroll 4
        for (int k4 = 0; k4 < 32; ++k4) {
            float4 hv = hp[k4];
            float4 w0 = wp[(k4 * 4 + 0) * 128];
            float4 w1 = wp[(k4 * 4 + 1) * 128];
            float4 w2 = wp[(k4 * 4 + 2) * 128];
            float4 w3 = wp[(k4 * 4 + 3) * 128];
            acc.x = fmaf(hv.x, w0.x, acc.x);
            acc.y = fmaf(hv.x, w0.y, acc.y);
            acc.z = fmaf(hv.x, w0.z, acc.z);
            acc.w = fmaf(hv.x, w0.w, acc.w);
            acc.x = fmaf(hv.y, w1.x, acc.x);
            acc.y = fmaf(hv.y, w1.y, acc.y);
            acc.z = fmaf(hv.y, w1.z, acc.z);
            acc.w = fmaf(hv.y, w1.w, acc.w);
            acc.x = fmaf(hv.z, w2.x, acc.x);
            acc.y = fmaf(hv.z, w2.y, acc.y);
            acc.z = fmaf(hv.z, w2.z, acc.z);
            acc.w = fmaf(hv.z, w2.w, acc.w);
            acc.x = fmaf(hv.w, w3.x, acc.x);
            acc.y = fmaf(hv.w, w3.y, acc.y);
            acc.z = fmaf(hv.w, w3.z, acc.z);
            acc.w = fmaf(hv.w, w3.w, acc.w);
        }

        if (g > 0) red[g - 1][l] = acc;
        __syncthreads();
        if (g == 0) {
            float4 r0 = red[0][l], r1 = red[1][l], r2 = red[2][l];
            float4 hv;
            hv.x = tanhf(acc.x + r0.x + r1.x + r2.x);
            hv.y = tanhf(acc.y + r0.y + r1.y + r2.y);
            hv.z = tanhf(acc.z + r0.z + r1.z + r2.z);
            hv.w = tanhf(acc.w + r0.w + r1.w + r2.w);
            hsh4[l] = hv;
            *((float4*)(hs + (b * TC + tt) * UU) + l) = hv;
        }
        __syncthreads();
    }

    if (tid < 128)
        ((float4*)(hcarry + b * UU))[tid] = hsh4[tid];
}

// ---------------- logits = hs @ Wd + bd (per chunk) ----------------
#define GM 64
#define GN 64
#define GK 16

__global__ __launch_bounds__(256) void logits_kernel(
    const float* __restrict__ A,    // [BB*TC, UU]
    const float* __restrict__ Wd,   // [UU, VV]
    const float* __restrict__ bd,   // [VV]
    float* __restrict__ out, int t0)
{
    __shared__ float As[GK][GM + 1];
    __shared__ float Bs[GK][GN + 1];
    const int tid  = threadIdx.x;
    const int row0 = blockIdx.x * GM;
    const int col0 = blockIdx.y * GN;
    const int tm = tid >> 4;     // 0..15
    const int tn = tid & 15;     // 0..15

    float acc[4][4] = {{0.f}};

    for (int k0 = 0; k0 < UU; k0 += GK) {
        #pragma unroll
        for (int i = 0; i < 4; ++i) {
            int lidx = i * 256 + tid;
            int r = lidx >> 4;
            int c = lidx & 15;
            As[c][r] = A[(row0 + r) * UU + k0 + c];
        }
        #pragma unroll
        for (int i = 0; i < 4; ++i) {
            int lidx = i * 256 + tid;
            int c = lidx >> 6;
            int n = lidx & 63;
            Bs[c][n] = Wd[(k0 + c) * VV + col0 + n];
        }
        __syncthreads();
        #pragma unroll
        for (int kk = 0; kk < GK; ++kk) {
            float av[4], bv[4];
            #pragma unroll
            for (int i = 0; i < 4; ++i) av[i] = As[kk][tm * 4 + i];
            #pragma unroll
            for (int j = 0; j < 4; ++j) bv[j] = Bs[kk][tn * 4 + j];
            #pragma unroll
            for (int i = 0; i < 4; ++i)
                #pragma unroll
                for (int j = 0; j < 4; ++j)
                    acc[i][j] = fmaf(av[i], bv[j], acc[i][j]);
        }
        __syncthreads();
    }

    #pragma unroll
    for (int i = 0; i < 4; ++i) {
        int r  = row0 + tm * 4 + i;
        int bb = r / TC;               // TC=128 -> shift
        int tt = r & (TC - 1);
        float4 res;
        res.x = acc[i][0] + bd[col0 + tn * 4 + 0];
        res.y = acc[i][1] + bd[col0 + tn * 4 + 1];
        res.z = acc[i][2] + bd[col0 + tn * 4 + 2];
        res.w = acc[i][3] + bd[col0 + tn * 4 + 3];
        *(float4*)(out + (size_t)(bb * TT_ + t0 + tt) * VV + col0 + tn * 4) = res;
    }
}

extern "C" void kernel_launch(void* const* d_in, const int* in_sizes, int n_in,
                              void* d_out, int out_size, void* d_ws, size_t ws_size,
                              hipStream_t stream)
{
    (void)in_sizes; (void)n_in; (void)out_size; (void)ws_size;

    const int*   toks = (const int*)  d_in[0];
    const float* emb  = (const float*)d_in[1];
    const float* Wx   = (const float*)d_in[2];
    const float* Wh   = (const float*)d_in[3];
    const float* bias = (const float*)d_in[4];
    const float* Wd   = (const float*)d_in[5];
    const float* bd   = (const float*)d_in[6];
    float* out = (float*)d_out;

    // workspace layout (floats): E2 [256*512] | hcarry [64*512] | hs [64*TC*512]
    float* E2     = (float*)d_ws;
    float* hcarry = E2 + EE * UU;
    float* hs     = hcarry + BB * UU;

    e2_kernel<<<EE, UU, 0, stream>>>(emb, Wx, bias, E2);

    for (int c = 0; c < TT_ / TC; ++c) {
        const int t0 = c * TC;
        rnn_chunk_kernel<<<BB, 512, 0, stream>>>(toks, E2, Wh, hcarry, hs, t0, c == 0);
        logits_kernel<<<dim3((BB * TC) / GM, VV / GN), 256, 0, stream>>>(hs, Wd, bd, out, t0);
    }
}